// Round 3
// baseline (424.379 us; speedup 1.0000x reference)
//
#include <hip/hip_runtime.h>
#include <hip/hip_bf16.h>

typedef __bf16 bf16_t;
typedef bf16_t bf16x8 __attribute__((ext_vector_type(8)));
typedef bf16_t bf16x4 __attribute__((ext_vector_type(4)));
typedef float f32x4 __attribute__((ext_vector_type(4)));

typedef __attribute__((address_space(1))) const void gconst_void;
typedef __attribute__((address_space(3))) void lds_void;

__device__ __forceinline__ void async16(const bf16_t* g, bf16_t* l) {
  __builtin_amdgcn_global_load_lds((gconst_void*)g, (lds_void*)l, 16, 0, 0);
}

// ---- batched f32 -> bf16 conversion (one launch for all tensors) ----
struct CvtDesc { const float* src; bf16_t* dst; long n; };
struct CvtArgs { CvtDesc d[10]; };

__global__ __launch_bounds__(256) void cvt_many(CvtArgs a) {
  const CvtDesc de = a.d[blockIdx.y];
  long i = ((long)blockIdx.x * 256 + threadIdx.x) * 4;
  const long stride = (long)gridDim.x * 256 * 4;
  for (; i < de.n; i += stride) {
    float4 v = *(const float4*)(de.src + i);
    bf16x4 o;
    o[0] = (bf16_t)v.x; o[1] = (bf16_t)v.y; o[2] = (bf16_t)v.z; o[3] = (bf16_t)v.w;
    *(bf16x4*)(de.dst + i) = o;
  }
}

// C[M,N] = act(A[M,K] @ W[N,K]^T + bias[N]); ACT: 0=none, 1=relu, 2=sigmoid
// M,N multiples of 128; K multiple of 32. bias is f32; OutT is float or bf16_t.
template <int ACT, bool HAS_BIAS, typename OutT>
__global__ __launch_bounds__(256) void gemm_bt(
    const bf16_t* __restrict__ A, const bf16_t* __restrict__ W,
    const float* __restrict__ bias, OutT* __restrict__ C,
    int M, int N, int K) {
  __shared__ __align__(16) bf16_t As[128 * 32];
  __shared__ __align__(16) bf16_t Bs[128 * 32];

  const int t = threadIdx.x;
  const int wave = t >> 6;
  const int lane = t & 63;
  const int quad = lane >> 4;
  const int l15 = lane & 15;

  const int bm = blockIdx.x * 128;
  const int bn = blockIdx.y * 128;
  const int wm = (wave >> 1) * 64;
  const int wn = (wave & 1) * 64;

  f32x4 acc[4][4];
#pragma unroll
  for (int i = 0; i < 4; ++i)
#pragma unroll
    for (int j = 0; j < 4; ++j) acc[i][j] = (f32x4){0.f, 0.f, 0.f, 0.f};

  // staging: 512 chunks of 16B per 128x32 tile; thread t does chunks t, t+256
  const int c0 = t, c1 = t + 256;
  const long ga0 = (long)(bm + (c0 >> 2)) * K + (c0 & 3) * 8;
  const long ga1 = (long)(bm + (c1 >> 2)) * K + (c1 & 3) * 8;
  const long gb0 = (long)(bn + (c0 >> 2)) * K + (c0 & 3) * 8;
  const long gb1 = (long)(bn + (c1 >> 2)) * K + (c1 & 3) * 8;
  bf16_t* lA0 = As + c0 * 8;
  bf16_t* lA1 = As + c1 * 8;
  bf16_t* lB0 = Bs + c0 * 8;
  bf16_t* lB1 = Bs + c1 * 8;

  for (int k0 = 0; k0 < K; k0 += 32) {
    __syncthreads();
    async16(A + ga0 + k0, lA0);
    async16(A + ga1 + k0, lA1);
    async16(W + gb0 + k0, lB0);
    async16(W + gb1 + k0, lB1);
    __syncthreads();  // compiler emits s_waitcnt vmcnt(0) before s_barrier

    bf16x8 af[4], bfr[4];
#pragma unroll
    for (int i = 0; i < 4; ++i)
      af[i] = *(const bf16x8*)&As[(wm + i * 16 + l15) * 32 + quad * 8];
#pragma unroll
    for (int j = 0; j < 4; ++j)
      bfr[j] = *(const bf16x8*)&Bs[(wn + j * 16 + l15) * 32 + quad * 8];
#pragma unroll
    for (int i = 0; i < 4; ++i)
#pragma unroll
      for (int j = 0; j < 4; ++j)
        acc[i][j] = __builtin_amdgcn_mfma_f32_16x16x32_bf16(af[i], bfr[j],
                                                            acc[i][j], 0, 0, 0);
  }

  // C/D layout: col = lane&15, row = quad*4 + reg   [measured m89/m91]
  const int row0 = bm + wm + quad * 4;
  const int col0 = bn + wn + l15;
#pragma unroll
  for (int j = 0; j < 4; ++j) {
    const int col = col0 + j * 16;
    float bv = 0.f;
    if (HAS_BIAS) bv = bias[col];
#pragma unroll
    for (int i = 0; i < 4; ++i) {
#pragma unroll
      for (int r = 0; r < 4; ++r) {
        float v = acc[i][j][r] + bv;
        if (ACT == 1) v = fmaxf(v, 0.f);
        if (ACT == 2) v = 1.f / (1.f + expf(-v));
        C[(long)(row0 + i * 16 + r) * N + col] = (OutT)v;
      }
    }
  }
}

// out[row] = sigmoid(dot(A[row,:], w) + b[0]); one wave per row; K mult of 512
__global__ __launch_bounds__(64) void rowdot_sig(
    const bf16_t* __restrict__ A, const float* __restrict__ w,
    const float* __restrict__ b, float* __restrict__ out, int K) {
  const int row = blockIdx.x;
  const int lane = threadIdx.x;
  const bf16_t* a = A + (long)row * K;
  float s = 0.f;
  for (int k = lane * 8; k < K; k += 64 * 8) {
    bf16x8 av = *(const bf16x8*)&a[k];
    float4 w0 = *(const float4*)&w[k];
    float4 w1 = *(const float4*)&w[k + 4];
    s += (float)av[0] * w0.x + (float)av[1] * w0.y +
         (float)av[2] * w0.z + (float)av[3] * w0.w +
         (float)av[4] * w1.x + (float)av[5] * w1.y +
         (float)av[6] * w1.z + (float)av[7] * w1.w;
  }
#pragma unroll
  for (int off = 32; off > 0; off >>= 1) s += __shfl_down(s, off);
  if (lane == 0) {
    float v = s + b[0];
    out[row] = 1.f / (1.f + expf(-v));
  }
}

__global__ __launch_bounds__(256) void minmax_part(
    const float* __restrict__ s, long n, float* __restrict__ pmin,
    float* __restrict__ pmax) {
  long i = ((long)blockIdx.x * 256 + threadIdx.x) * 4;
  const long stride = (long)gridDim.x * 256 * 4;
  float mn = 3.4e38f, mx = -3.4e38f;
  for (; i < n; i += stride) {
    float4 v = *(const float4*)&s[i];
    mn = fminf(mn, fminf(fminf(v.x, v.y), fminf(v.z, v.w)));
    mx = fmaxf(mx, fmaxf(fmaxf(v.x, v.y), fmaxf(v.z, v.w)));
  }
#pragma unroll
  for (int off = 32; off > 0; off >>= 1) {
    mn = fminf(mn, __shfl_down(mn, off));
    mx = fmaxf(mx, __shfl_down(mx, off));
  }
  __shared__ float smn[4], smx[4];
  const int wv = threadIdx.x >> 6, ln = threadIdx.x & 63;
  if (ln == 0) { smn[wv] = mn; smx[wv] = mx; }
  __syncthreads();
  if (threadIdx.x == 0) {
    pmin[blockIdx.x] = fminf(fminf(smn[0], smn[1]), fminf(smn[2], smn[3]));
    pmax[blockIdx.x] = fmaxf(fmaxf(smx[0], smx[1]), fmaxf(smx[2], smx[3]));
  }
}

__global__ __launch_bounds__(256) void minmax_final(
    const float* __restrict__ pmin, const float* __restrict__ pmax, int nb,
    float* __restrict__ res) {
  float mn = 3.4e38f, mx = -3.4e38f;
  for (int i = threadIdx.x; i < nb; i += 256) {
    mn = fminf(mn, pmin[i]);
    mx = fmaxf(mx, pmax[i]);
  }
#pragma unroll
  for (int off = 32; off > 0; off >>= 1) {
    mn = fminf(mn, __shfl_down(mn, off));
    mx = fmaxf(mx, __shfl_down(mx, off));
  }
  __shared__ float smn[4], smx[4];
  const int wv = threadIdx.x >> 6, ln = threadIdx.x & 63;
  if (ln == 0) { smn[wv] = mn; smx[wv] = mx; }
  __syncthreads();
  if (threadIdx.x == 0) {
    float m0 = fminf(fminf(smn[0], smn[1]), fminf(smn[2], smn[3]));
    float m1 = fmaxf(fmaxf(smx[0], smx[1]), fmaxf(smx[2], smx[3]));
    res[0] = m0;
    res[1] = 1.f / (m1 - m0);
  }
}

// in-place: out[i] = (out[i] - mn) * inv
__global__ __launch_bounds__(256) void normalize_k(
    float* __restrict__ out, const float* __restrict__ res, long n) {
  const float mn = res[0], inv = res[1];
  long i = ((long)blockIdx.x * 256 + threadIdx.x) * 4;
  const long stride = (long)gridDim.x * 256 * 4;
  for (; i < n; i += stride) {
    float4 v = *(const float4*)&out[i];
    v.x = (v.x - mn) * inv;
    v.y = (v.y - mn) * inv;
    v.z = (v.z - mn) * inv;
    v.w = (v.w - mn) * inv;
    *(float4*)&out[i] = v;
  }
}

extern "C" void kernel_launch(void* const* d_in, const int* in_sizes, int n_in,
                              void* d_out, int out_size, void* d_ws,
                              size_t ws_size, hipStream_t stream) {
  // Reference is float32 end-to-end -> inputs/outputs are f32 per harness rules.
  const float* x1   = (const float*)d_in[0];   // [4096,1024]
  const float* x2   = (const float*)d_in[1];   // [4096,512]
  const float* W1_1 = (const float*)d_in[2];   const float* b1_1 = (const float*)d_in[3];
  const float* W1_2 = (const float*)d_in[4];   const float* b1_2 = (const float*)d_in[5];
  const float* W1_3 = (const float*)d_in[6];   const float* b1_3 = (const float*)d_in[7];
  const float* W1_4 = (const float*)d_in[8];   const float* b1_4 = (const float*)d_in[9];
  const float* W1_5 = (const float*)d_in[10];  const float* b1_5 = (const float*)d_in[11];
  const float* Wp1  = (const float*)d_in[12];  const float* bp1  = (const float*)d_in[13];
  const float* W2_1 = (const float*)d_in[14];  const float* b2_1 = (const float*)d_in[15];
  const float* W2_2 = (const float*)d_in[16];  const float* b2_2 = (const float*)d_in[17];
  const float* W2_3 = (const float*)d_in[18];  const float* b2_3 = (const float*)d_in[19];
  const float* Wp2  = (const float*)d_in[20];  const float* bp2  = (const float*)d_in[21];

  float* out = (float*)d_out;
  float* out_pre_data  = out;                             // [4096]
  float* out_pre_dm    = out + 4096;                      // [4096*4096] f32 = 64 MB
  float* out_pre_model = out + 4096 + (long)4096 * 4096;  // [4096]

  // The 64 MB pre_dm region is dead until the scores GEMM -> use it as the
  // staging arena for converted bf16 tensors and intermediates. Stream order
  // guarantees all reads of this arena precede the scores GEMM's writes.
  char* arena = (char*)out_pre_dm;
  const size_t MB = 1024 * 1024;
  bf16_t* x1b   = (bf16_t*)(arena);             // 8 MB  [4096,1024]
  bf16_t* x2b   = (bf16_t*)(arena + 8 * MB);    // 4 MB  [4096,512]
  bf16_t* W1_1b = (bf16_t*)(arena + 12 * MB);   // 4 MB  [2048,1024]
  bf16_t* W1_2b = (bf16_t*)(arena + 16 * MB);   // 4 MB  [1024,2048]
  bf16_t* W1_3b = (bf16_t*)(arena + 20 * MB);   // 1 MB  [512,1024]
  bf16_t* W1_4b = (bf16_t*)(arena + 21 * MB);   // 1 MB  [1024,512]
  bf16_t* W1_5b = (bf16_t*)(arena + 22 * MB);   // 4 MB  [2048,1024]
  bf16_t* W2_1b = (bf16_t*)(arena + 26 * MB);   // 1 MB  [1024,512]
  bf16_t* W2_2b = (bf16_t*)(arena + 27 * MB);   // 1 MB  [512,1024]
  bf16_t* W2_3b = (bf16_t*)(arena + 28 * MB);   // 1 MB  [1024,512]
  bf16_t* bufA  = (bf16_t*)(arena + 32 * MB);   // 16 MB [4096,2048]
  bf16_t* bufB  = (bf16_t*)(arena + 48 * MB);   // 8 MB  [4096,1024]

  // d_ws: only the tensors live during the scores GEMM + reduction partials
  char* ws = (char*)d_ws;
  bf16_t* bufX1 = (bf16_t*)(ws);            // 4 MB [4096,512]
  bf16_t* bufX2 = (bf16_t*)(ws + 4 * MB);   // 4 MB [4096,512]
  float* pmin = (float*)(ws + 8 * MB);      // 4 KB
  float* pmax = pmin + 1024;                // 4 KB
  float* res  = pmax + 1024;                // 8 B

  CvtArgs ca;
  ca.d[0] = {x1,   x1b,   (long)4096 * 1024};
  ca.d[1] = {x2,   x2b,   (long)4096 * 512};
  ca.d[2] = {W1_1, W1_1b, (long)2048 * 1024};
  ca.d[3] = {W1_2, W1_2b, (long)1024 * 2048};
  ca.d[4] = {W1_3, W1_3b, (long)512 * 1024};
  ca.d[5] = {W1_4, W1_4b, (long)1024 * 512};
  ca.d[6] = {W1_5, W1_5b, (long)2048 * 1024};
  ca.d[7] = {W2_1, W2_1b, (long)1024 * 512};
  ca.d[8] = {W2_2, W2_2b, (long)512 * 1024};
  ca.d[9] = {W2_3, W2_3b, (long)1024 * 512};

  const dim3 blk(256);
  const long nS = (long)4096 * 4096;

  cvt_many<<<dim3(128, 10), blk, 0, stream>>>(ca);

  // branch 1
  gemm_bt<1, true, bf16_t><<<dim3(32, 16), blk, 0, stream>>>(x1b, W1_1b, b1_1, bufA, 4096, 2048, 1024);
  gemm_bt<1, true, bf16_t><<<dim3(32, 8),  blk, 0, stream>>>(bufA, W1_2b, b1_2, bufB, 4096, 1024, 2048);
  gemm_bt<2, true, bf16_t><<<dim3(32, 4),  blk, 0, stream>>>(bufB, W1_3b, b1_3, bufX1, 4096, 512, 1024);
  gemm_bt<1, true, bf16_t><<<dim3(32, 8),  blk, 0, stream>>>(bufX1, W1_4b, b1_4, bufB, 4096, 1024, 512);
  gemm_bt<1, true, bf16_t><<<dim3(32, 16), blk, 0, stream>>>(bufB, W1_5b, b1_5, bufA, 4096, 2048, 1024);
  rowdot_sig<<<4096, 64, 0, stream>>>(bufA, Wp1, bp1, out_pre_data, 2048);

  // branch 2
  gemm_bt<1, true, bf16_t><<<dim3(32, 8), blk, 0, stream>>>(x2b, W2_1b, b2_1, bufB, 4096, 1024, 512);
  gemm_bt<2, true, bf16_t><<<dim3(32, 4), blk, 0, stream>>>(bufB, W2_2b, b2_2, bufX2, 4096, 512, 1024);
  gemm_bt<1, true, bf16_t><<<dim3(32, 8), blk, 0, stream>>>(bufX2, W2_3b, b2_3, bufB, 4096, 1024, 512);
  rowdot_sig<<<4096, 64, 0, stream>>>(bufB, Wp2, bp2, out_pre_model, 1024);

  // scores (f32 out) over the whole arena, then min-max normalize in place
  gemm_bt<0, false, float><<<dim3(32, 32), blk, 0, stream>>>(bufX1, bufX2, nullptr, out_pre_dm, 4096, 4096, 512);
  minmax_part<<<1024, blk, 0, stream>>>(out_pre_dm, nS, pmin, pmax);
  minmax_final<<<1, blk, 0, stream>>>(pmin, pmax, 1024, res);
  normalize_k<<<1024, blk, 0, stream>>>(out_pre_dm, res, nS);
}

// Round 4
// 360.478 us; speedup vs baseline: 1.1773x; 1.1773x over previous
//
#include <hip/hip_runtime.h>
#include <hip/hip_bf16.h>

typedef __bf16 bf16_t;
typedef bf16_t bf16x8 __attribute__((ext_vector_type(8)));
typedef bf16_t bf16x4 __attribute__((ext_vector_type(4)));
typedef float f32x4 __attribute__((ext_vector_type(4)));

typedef __attribute__((address_space(1))) const void gconst_void;
typedef __attribute__((address_space(3))) void lds_void;

__device__ __forceinline__ void async16(const bf16_t* g, bf16_t* l) {
  __builtin_amdgcn_global_load_lds((gconst_void*)g, (lds_void*)l, 16, 0, 0);
}

// ---- batched f32 -> bf16 conversion ----
struct CvtDesc { const float* src; bf16_t* dst; long n; };
struct CvtArgs { CvtDesc d[10]; };

__global__ __launch_bounds__(256) void cvt_many(CvtArgs a) {
  const CvtDesc de = a.d[blockIdx.y];
  long i = ((long)blockIdx.x * 256 + threadIdx.x) * 4;
  const long stride = (long)gridDim.x * 256 * 4;
  for (; i < de.n; i += stride) {
    float4 v = *(const float4*)(de.src + i);
    bf16x4 o;
    o[0] = (bf16_t)v.x; o[1] = (bf16_t)v.y; o[2] = (bf16_t)v.z; o[3] = (bf16_t)v.w;
    *(bf16x4*)(de.dst + i) = o;
  }
}

// ---- grouped GEMM: C[4096,N] = act(A[4096,K] @ W[N,K]^T + bias) ----
// M fixed 4096 (32 row-tiles), N mult of 128, K mult of 32.
// act: 0=none 1=relu 2=sigmoid. Up to 2 independent problems per launch.
struct GDesc {
  const bf16_t* A; const bf16_t* W; const float* bias; void* C;
  int N, K, act;
};
struct GArgs { GDesc d[2]; int ntiles0; };

template <typename OutT, bool MINMAX>
__global__ __launch_bounds__(256) void gemm_gb(GArgs ga, float* __restrict__ pmin,
                                               float* __restrict__ pmax) {
  const int b = blockIdx.x;
  const int p = (b >= ga.ntiles0) ? 1 : 0;
  const GDesc d = ga.d[p];
  const int local = b - (p ? ga.ntiles0 : 0);
  const int bm = (local & 31) * 128;   // 32 row tiles (M=4096)
  const int bn = (local >> 5) * 128;
  const int N = d.N, K = d.K;

  // double-buffered LDS tiles, 32 KB total
  __shared__ __align__(16) bf16_t As[2][128 * 32];
  __shared__ __align__(16) bf16_t Bs[2][128 * 32];

  const int t = threadIdx.x;
  const int wave = t >> 6;
  const int lane = t & 63;
  const int quad = lane >> 4;
  const int l15 = lane & 15;
  const int wm = (wave >> 1) * 64;
  const int wn = (wave & 1) * 64;

  f32x4 acc[4][4];
#pragma unroll
  for (int i = 0; i < 4; ++i)
#pragma unroll
    for (int j = 0; j < 4; ++j) acc[i][j] = (f32x4){0.f, 0.f, 0.f, 0.f};

  // Staging: 512 16B-chunks per 128x32 tile; thread t stages chunks t, t+256.
  // LDS slot s of row r holds global k-chunk (s - r) & 3 (rotation swizzle,
  // expressible with global_load_lds's lane-linear LDS addressing; reader
  // uses slot (quad + r) & 3). 8-way -> 4-way bank conflicts.
  const int c0 = t, c1 = t + 256;
  const int r0 = c0 >> 2, kc0 = ((c0 & 3) - r0) & 3;
  const int r1 = c1 >> 2, kc1 = ((c1 & 3) - r1) & 3;
  const bf16_t* pa0 = d.A + (long)(bm + r0) * K + kc0 * 8;
  const bf16_t* pa1 = d.A + (long)(bm + r1) * K + kc1 * 8;
  const bf16_t* pw0 = d.W + (long)(bn + r0) * K + kc0 * 8;
  const bf16_t* pw1 = d.W + (long)(bn + r1) * K + kc1 * 8;
  bf16_t* lA0 = &As[0][c0 * 8]; bf16_t* lA1 = &As[0][c1 * 8];
  bf16_t* lB0 = &Bs[0][c0 * 8]; bf16_t* lB1 = &Bs[0][c1 * 8];
  const int bufOff = 128 * 32;  // elements between buffer 0 and 1

  // prologue: stage k0=0 into buffer 0
  async16(pa0, lA0); async16(pa1, lA1);
  async16(pw0, lB0); async16(pw1, lB1);

  int buf = 0;
  for (int k0 = 0; k0 < K; k0 += 32) {
    __syncthreads();  // drains vmcnt(0): the stage issued last iter (or prologue)
    const int kn = k0 + 32;
    if (kn < K) {  // prefetch next tile into the other buffer; flies during compute
      const int o = (buf ^ 1) * bufOff;
      async16(pa0 + kn, lA0 + o); async16(pa1 + kn, lA1 + o);
      async16(pw0 + kn, lB0 + o); async16(pw1 + kn, lB1 + o);
    }
    const bf16_t* as = As[buf];
    const bf16_t* bs = Bs[buf];
    bf16x8 af[4], bfr[4];
#pragma unroll
    for (int i = 0; i < 4; ++i) {
      const int r = wm + i * 16 + l15;
      af[i] = *(const bf16x8*)&as[r * 32 + ((quad + r) & 3) * 8];
    }
#pragma unroll
    for (int j = 0; j < 4; ++j) {
      const int r = wn + j * 16 + l15;
      bfr[j] = *(const bf16x8*)&bs[r * 32 + ((quad + r) & 3) * 8];
    }
#pragma unroll
    for (int i = 0; i < 4; ++i)
#pragma unroll
      for (int j = 0; j < 4; ++j)
        acc[i][j] = __builtin_amdgcn_mfma_f32_16x16x32_bf16(af[i], bfr[j],
                                                            acc[i][j], 0, 0, 0);
    buf ^= 1;
  }

  // C/D layout: col = lane&15, row = quad*4 + reg   [measured m89/m91]
  OutT* C = (OutT*)d.C;
  const int row0 = bm + wm + quad * 4;
  const int col0 = bn + wn + l15;
  float mn = 3.4e38f, mx = -3.4e38f;
#pragma unroll
  for (int j = 0; j < 4; ++j) {
    const int col = col0 + j * 16;
    const float bv = d.bias ? d.bias[col] : 0.f;
#pragma unroll
    for (int i = 0; i < 4; ++i) {
#pragma unroll
      for (int r = 0; r < 4; ++r) {
        float v = acc[i][j][r] + bv;
        if (d.act == 1) v = fmaxf(v, 0.f);
        else if (d.act == 2) v = 1.f / (1.f + expf(-v));
        C[(long)(row0 + i * 16 + r) * N + col] = (OutT)v;
        if (MINMAX) { mn = fminf(mn, v); mx = fmaxf(mx, v); }
      }
    }
  }
  if (MINMAX) {
#pragma unroll
    for (int off = 32; off > 0; off >>= 1) {
      mn = fminf(mn, __shfl_down(mn, off));
      mx = fmaxf(mx, __shfl_down(mx, off));
    }
    __shared__ float smn[4], smx[4];
    if (lane == 0) { smn[wave] = mn; smx[wave] = mx; }
    __syncthreads();
    if (t == 0) {
      pmin[blockIdx.x] = fminf(fminf(smn[0], smn[1]), fminf(smn[2], smn[3]));
      pmax[blockIdx.x] = fmaxf(fmaxf(smx[0], smx[1]), fmaxf(smx[2], smx[3]));
    }
  }
}

// ---- merged projection dots: out[row] = sigmoid(dot(A[row], w) + b) ----
struct RDesc { const bf16_t* A; const float* w; const float* b; float* out; int K; };

__global__ __launch_bounds__(64) void rowdot2(RDesc d0, RDesc d1) {
  const RDesc d = blockIdx.y ? d1 : d0;
  const int row = blockIdx.x;
  const int lane = threadIdx.x;
  const bf16_t* a = d.A + (long)row * d.K;
  float s = 0.f;
  for (int k = lane * 8; k < d.K; k += 64 * 8) {
    bf16x8 av = *(const bf16x8*)&a[k];
    float4 w0 = *(const float4*)&d.w[k];
    float4 w1 = *(const float4*)&d.w[k + 4];
    s += (float)av[0] * w0.x + (float)av[1] * w0.y +
         (float)av[2] * w0.z + (float)av[3] * w0.w +
         (float)av[4] * w1.x + (float)av[5] * w1.y +
         (float)av[6] * w1.z + (float)av[7] * w1.w;
  }
#pragma unroll
  for (int off = 32; off > 0; off >>= 1) s += __shfl_down(s, off);
  if (lane == 0) d.out[row] = 1.f / (1.f + expf(-(s + d.b[0])));
}

__global__ __launch_bounds__(256) void minmax_final(
    const float* __restrict__ pmin, const float* __restrict__ pmax, int nb,
    float* __restrict__ res) {
  float mn = 3.4e38f, mx = -3.4e38f;
  for (int i = threadIdx.x; i < nb; i += 256) {
    mn = fminf(mn, pmin[i]);
    mx = fmaxf(mx, pmax[i]);
  }
#pragma unroll
  for (int off = 32; off > 0; off >>= 1) {
    mn = fminf(mn, __shfl_down(mn, off));
    mx = fmaxf(mx, __shfl_down(mx, off));
  }
  __shared__ float smn[4], smx[4];
  const int wv = threadIdx.x >> 6, ln = threadIdx.x & 63;
  if (ln == 0) { smn[wv] = mn; smx[wv] = mx; }
  __syncthreads();
  if (threadIdx.x == 0) {
    float m0 = fminf(fminf(smn[0], smn[1]), fminf(smn[2], smn[3]));
    float m1 = fmaxf(fmaxf(smx[0], smx[1]), fmaxf(smx[2], smx[3]));
    res[0] = m0;
    res[1] = 1.f / (m1 - m0);
  }
}

__global__ __launch_bounds__(256) void normalize_k(
    float* __restrict__ out, const float* __restrict__ res, long n) {
  const float mn = res[0], inv = res[1];
  long i = ((long)blockIdx.x * 256 + threadIdx.x) * 4;
  const long stride = (long)gridDim.x * 256 * 4;
  for (; i < n; i += stride) {
    float4 v = *(const float4*)&out[i];
    v.x = (v.x - mn) * inv;
    v.y = (v.y - mn) * inv;
    v.z = (v.z - mn) * inv;
    v.w = (v.w - mn) * inv;
    *(float4*)&out[i] = v;
  }
}

extern "C" void kernel_launch(void* const* d_in, const int* in_sizes, int n_in,
                              void* d_out, int out_size, void* d_ws,
                              size_t ws_size, hipStream_t stream) {
  const float* x1   = (const float*)d_in[0];
  const float* x2   = (const float*)d_in[1];
  const float* W1_1 = (const float*)d_in[2];   const float* b1_1 = (const float*)d_in[3];
  const float* W1_2 = (const float*)d_in[4];   const float* b1_2 = (const float*)d_in[5];
  const float* W1_3 = (const float*)d_in[6];   const float* b1_3 = (const float*)d_in[7];
  const float* W1_4 = (const float*)d_in[8];   const float* b1_4 = (const float*)d_in[9];
  const float* W1_5 = (const float*)d_in[10];  const float* b1_5 = (const float*)d_in[11];
  const float* Wp1  = (const float*)d_in[12];  const float* bp1  = (const float*)d_in[13];
  const float* W2_1 = (const float*)d_in[14];  const float* b2_1 = (const float*)d_in[15];
  const float* W2_2 = (const float*)d_in[16];  const float* b2_2 = (const float*)d_in[17];
  const float* W2_3 = (const float*)d_in[18];  const float* b2_3 = (const float*)d_in[19];
  const float* Wp2  = (const float*)d_in[20];  const float* bp2  = (const float*)d_in[21];

  float* out = (float*)d_out;
  float* out_pre_data  = out;
  float* out_pre_dm    = out + 4096;                      // 64 MB f32
  float* out_pre_model = out + 4096 + (long)4096 * 4096;

  // 64 MB arena inside the (dead until scores) pre_dm output region.
  char* arena = (char*)out_pre_dm;
  const size_t MB = 1024 * 1024;
  bf16_t* x1b   = (bf16_t*)(arena);            // 8 MB  [4096,1024]
  bf16_t* x2b   = (bf16_t*)(arena + 8 * MB);   // 4 MB  [4096,512]
  bf16_t* W1_1b = (bf16_t*)(arena + 12 * MB);  // 4 MB
  bf16_t* W1_2b = (bf16_t*)(arena + 16 * MB);  // 4 MB
  bf16_t* W1_3b = (bf16_t*)(arena + 20 * MB);  // 1 MB
  bf16_t* W1_4b = (bf16_t*)(arena + 21 * MB);  // 1 MB
  bf16_t* W1_5b = (bf16_t*)(arena + 22 * MB);  // 4 MB
  bf16_t* W2_1b = (bf16_t*)(arena + 26 * MB);  // 1 MB
  bf16_t* W2_2b = (bf16_t*)(arena + 27 * MB);  // 1 MB
  bf16_t* W2_3b = (bf16_t*)(arena + 28 * MB);  // 1 MB
  bf16_t* bufA  = (bf16_t*)(arena + 32 * MB);  // 16 MB [4096,2048] B1 even
  bf16_t* bufB  = (bf16_t*)(arena + 48 * MB);  // 8 MB  [4096,1024] B1 odd
  bf16_t* bufC  = (bf16_t*)(arena + 56 * MB);  // 8 MB  [4096,1024] B2

  char* ws = (char*)d_ws;  // ~8 MB used (known-safe; 16 MB worked in R3)
  bf16_t* bufX1 = (bf16_t*)(ws);            // 4 MB [4096,512]
  bf16_t* bufX2 = (bf16_t*)(ws + 4 * MB);   // 4 MB [4096,512]
  float* pmin = (float*)(ws + 8 * MB);
  float* pmax = pmin + 1024;
  float* res  = pmax + 1024;

  CvtArgs ca;
  ca.d[0] = {x1,   x1b,   (long)4096 * 1024};
  ca.d[1] = {x2,   x2b,   (long)4096 * 512};
  ca.d[2] = {W1_1, W1_1b, (long)2048 * 1024};
  ca.d[3] = {W1_2, W1_2b, (long)1024 * 2048};
  ca.d[4] = {W1_3, W1_3b, (long)512 * 1024};
  ca.d[5] = {W1_4, W1_4b, (long)1024 * 512};
  ca.d[6] = {W1_5, W1_5b, (long)2048 * 1024};
  ca.d[7] = {W2_1, W2_1b, (long)1024 * 512};
  ca.d[8] = {W2_2, W2_2b, (long)512 * 1024};
  ca.d[9] = {W2_3, W2_3b, (long)1024 * 512};
  cvt_many<<<dim3(192, 10), 256, 0, stream>>>(ca);

  const long nS = (long)4096 * 4096;
  GArgs g;

  // G1: B1L1 (relu, 512 tiles) + B2L1 (relu, 256 tiles)
  g.d[0] = {x1b, W1_1b, b1_1, bufA, 2048, 1024, 1};
  g.d[1] = {x2b, W2_1b, b2_1, bufC, 1024, 512, 1};
  g.ntiles0 = 512;
  gemm_gb<bf16_t, false><<<768, 256, 0, stream>>>(g, nullptr, nullptr);

  // G2: B1L2 (relu, 256) + B2L2 (sigmoid, 128)
  g.d[0] = {bufA, W1_2b, b1_2, bufB, 1024, 2048, 1};
  g.d[1] = {bufC, W2_2b, b2_2, bufX2, 512, 1024, 2};
  g.ntiles0 = 256;
  gemm_gb<bf16_t, false><<<384, 256, 0, stream>>>(g, nullptr, nullptr);

  // G3: B1L3 (sigmoid, 128) + B2L3 (relu, 256)
  g.d[0] = {bufB, W1_3b, b1_3, bufX1, 512, 1024, 2};
  g.d[1] = {bufX2, W2_3b, b2_3, bufC, 1024, 512, 1};
  g.ntiles0 = 128;
  gemm_gb<bf16_t, false><<<384, 256, 0, stream>>>(g, nullptr, nullptr);

  // B1L4 (relu, 256)
  g.d[0] = {bufX1, W1_4b, b1_4, bufB, 1024, 512, 1};
  g.d[1] = g.d[0];
  g.ntiles0 = 256;
  gemm_gb<bf16_t, false><<<256, 256, 0, stream>>>(g, nullptr, nullptr);

  // B1L5 (relu, 512)
  g.d[0] = {bufB, W1_5b, b1_5, bufA, 2048, 1024, 1};
  g.d[1] = g.d[0];
  g.ntiles0 = 512;
  gemm_gb<bf16_t, false><<<512, 256, 0, stream>>>(g, nullptr, nullptr);

  // both projections
  RDesc r0 = {bufA, Wp1, bp1, out_pre_data, 2048};
  RDesc r1 = {bufC, Wp2, bp2, out_pre_model, 1024};
  rowdot2<<<dim3(4096, 2), 64, 0, stream>>>(r0, r1);

  // scores (f32, fused per-block min/max partials), overwrites the arena
  g.d[0] = {bufX1, bufX2, nullptr, out_pre_dm, 4096, 512, 0};
  g.d[1] = g.d[0];
  g.ntiles0 = 1024;
  gemm_gb<float, true><<<1024, 256, 0, stream>>>(g, pmin, pmax);

  minmax_final<<<1, 256, 0, stream>>>(pmin, pmax, 1024, res);
  normalize_k<<<2048, 256, 0, stream>>>(out_pre_dm, res, nS);
}